// Round 8
// baseline (276.481 us; speedup 1.0000x reference)
//
#include <hip/hip_runtime.h>
#include <hip/hip_bf16.h>
#include <cstdint>
#include <cstddef>

#define K_DIM 4096

typedef __bf16 bf16x8 __attribute__((ext_vector_type(8)));
typedef float  f32x4  __attribute__((ext_vector_type(4)));
typedef unsigned short ushort8 __attribute__((ext_vector_type(8)));

struct KronPtrs { const float* a[8]; const float* b[8]; };

// ---------------------------------------------------------------------------
// Fused prologue (unchanged).
// ---------------------------------------------------------------------------
__global__ __launch_bounds__(256) void prologue_kernel(
        KronPtrs P,
        const float* __restrict__ x,
        __hip_bfloat16* __restrict__ Wb,
        __hip_bfloat16* __restrict__ Xb)
{
    __shared__ __align__(16) float sa[1080];
    __shared__ __align__(16) float sb[1080];

    const int tid = threadIdx.x;

    if (blockIdx.x < 8192) {
        const size_t t = (size_t)blockIdx.x * 256 + tid;
        const size_t o = t * 8;
        const float4 v0 = *(const float4*)(x + o);
        const float4 v1 = *(const float4*)(x + o + 4);
        union { __hip_bfloat16 h[8]; ushort8 v; } u;
        u.h[0] = __float2bfloat16(v0.x);
        u.h[1] = __float2bfloat16(v0.y);
        u.h[2] = __float2bfloat16(v0.z);
        u.h[3] = __float2bfloat16(v0.w);
        u.h[4] = __float2bfloat16(v1.x);
        u.h[5] = __float2bfloat16(v1.y);
        u.h[6] = __float2bfloat16(v1.z);
        u.h[7] = __float2bfloat16(v1.w);
        *(ushort8*)(void*)(Xb + o) = u.v;
        return;
    }

    const int row = blockIdx.x - 8192;

#define STAGE(IDX, MA, LB, OA, OB)                                             \
    {                                                                          \
        const int mb_ = 1 << (LB);                                             \
        const float* ap = P.a[IDX] + (size_t)(row >> (LB)) * (MA);             \
        const float* bp = P.b[IDX] + (size_t)(row & (mb_ - 1)) * mb_;          \
        for (int i = tid; i < (MA); i += 256) sa[(OA) + i] = ap[i];            \
        for (int i = tid; i < mb_;  i += 256) sb[(OB) + i] = bp[i];            \
    }

    STAGE(0,  64, 6,   0,    0)
    STAGE(1,  64, 6,  64,   64)
    STAGE(2,  32, 7, 128,  128)
    STAGE(3, 128, 5, 160,  256)
    STAGE(4,  16, 8, 288,  288)
    STAGE(5, 256, 4, 304,  544)
    STAGE(6,   8, 9, 560,  560)
    STAGE(7, 512, 3, 568, 1072)
#undef STAGE

    __syncthreads();

    const float s = 0.17677669529663687f;  // 1 / (2*sqrt(8))
    const int q0 = tid << 4;

#pragma unroll
    for (int g = 0; g < 2; ++g) {
        const int q8 = q0 + (g << 3);
        float acc[8] = {0.f,0.f,0.f,0.f,0.f,0.f,0.f,0.f};

#define KTERM(LB, OA, OB)                                                      \
    {                                                                          \
        const int mb_   = 1 << (LB);                                           \
        const float av  = sa[(OA) + (q8 >> (LB))];                             \
        const float* bp = sb + (OB) + (q8 & (mb_ - 1));                        \
        const float4 x0 = *(const float4*)(bp);                                \
        const float4 x1 = *(const float4*)(bp + 4);                            \
        acc[0] += av * x0.x; acc[1] += av * x0.y;                              \
        acc[2] += av * x0.z; acc[3] += av * x0.w;                              \
        acc[4] += av * x1.x; acc[5] += av * x1.y;                              \
        acc[6] += av * x1.z; acc[7] += av * x1.w;                              \
    }

        KTERM(6,   0,    0)
        KTERM(6,  64,   64)
        KTERM(7, 128,  128)
        KTERM(5, 160,  256)
        KTERM(8, 288,  288)
        KTERM(4, 304,  544)
        KTERM(9, 560,  560)
        KTERM(3, 568, 1072)
#undef KTERM

        union { __hip_bfloat16 h[8]; ushort8 v; } u;
#pragma unroll
        for (int i = 0; i < 8; ++i) u.h[i] = __float2bfloat16(acc[i] * s);
        *(ushort8*)(void*)(Wb + (size_t)row * K_DIM + q8) = u.v;
    }
}

// ---------------------------------------------------------------------------
// GEMM R11: back to the R8-GREEN 4-phase skeleton (one MMA cluster/phase),
// with (1) HARDENED BARRIERS and (2) balanced reads + earlier vmcnt.
//
// THE R9/R10 RACE (root cause): s_barrier has NO memory effects in LLVM's
// model, so ds_reads placed after a barrier can legally hoist to between the
// per-wave vmcnt and the s_barrier — where THIS wave has drained the next
// tile but OTHER waves' DMA stores may still be landing. sched_barrier(0)
// (R10) only constrains the machine scheduler; it missed the motion. Fix:
// BAR() = s_barrier + empty asm volatile "memory" — a zero-instruction
// compiler-level memory fence. Every phase is now bracketed by asm memory
// fences, making every counted-wait assumption robust to legal motion.
//
// Per tile t (buffer p, q=p^1); frags: af[m-half][kk][mi], bf[n-half][kk][ni];
// MMA(m,n) = af[m] x bf[n]. Reads/phase = 4/8/8/4 (R8 was 4/8/0/12 — the
// 12-burst overran the 620-cyc MMA window; that was R8's residual stall):
//  ph0: lgkm(0) [drain prev read-ahead];  read B1(p)[4];  MMA(0,0); BAR
//  ph1: read A1(p)[8]; stageA0(t+2);  lgkm(8) [B1 done];  MMA(0,1);
//       vmcnt(2) [outst = t+1's 8 + A0stage 2 = 10 -> completes t+1]; BAR
//  ph2: read nA0(q)[8] [t+1 landed+fenced]; stageB0,B1(t+2);
//       lgkm(8) [A1 done];  MMA(1,0) [bf[0] = t's B0, not yet clobbered]; BAR
//  ph3: read nB0(q)[4] [clobbers bf[0] one barrier after MMA(1,0)];
//       stageA1(t+2);  MMA(1,1); BAR
// WAR audit: B1 reads done (ph1 lgkm8) before stageB1 issue (ph2, +1 bar);
// A1 done (ph2 lgkm8) before stageA1 (ph3); nA0/nB0 done (next ph0 lgkm0)
// before stageA0/B0 (next ph1/ph2). All stages/reads pinned in-phase by the
// asm fences. Tail: tile62 VM(0) drains tile63; tile63 LG2=lgkm(0), no RA.
// ---------------------------------------------------------------------------
__device__ __forceinline__ void gload_lds16(const void* g, void* l)
{
    __builtin_amdgcn_global_load_lds((const __attribute__((address_space(1))) void*)g,
                                     (__attribute__((address_space(3))) void*)l,
                                     16, 0, 0);
}

__global__ __launch_bounds__(512) void gemm_kernel(
        const __hip_bfloat16* __restrict__ Wb,
        const __hip_bfloat16* __restrict__ Xb,
        const float* __restrict__ bias,
        float* __restrict__ C)
{
    // [buf*2 + half][128 rows * 64 cols]
    __shared__ __align__(16) __hip_bfloat16 lsA[4][8192];   // 64 KiB
    __shared__ __align__(16) __hip_bfloat16 lsB[4][8192];   // 64 KiB

    const int tid  = threadIdx.x;
    const int lane = tid & 63;
    const int wid  = tid >> 6;    // 0..7
    const int swid = __builtin_amdgcn_readfirstlane(wid);   // wave-uniform SGPR
    const int wr   = wid >> 2;    // 0..1 (M)
    const int wc   = wid & 3;     // 0..3 (N)

    // XCD-aware bijective swizzle of the 256-block grid (16x16 tiles).
    const int bid = blockIdx.x;
    const int lin = (bid & 7) * 32 + (bid >> 3);
    const int bm  = (lin >> 4) << 8;
    const int bn  = (lin & 15) << 8;

    // --- staging addressing: scalar bases + ONE per-lane offset ---
    const int sr = lane >> 3;            // row within 8-row chunk
    const int lc = (lane & 7) ^ sr;      // logical 16B chunk to fetch (swizzle)
    const int loff = sr * K_DIM + lc * 8;                 // per-lane, 1 VGPR
    const size_t aoffu = (size_t)(bm + swid * 8) * K_DIM; // SGPR
    const size_t boffu = (size_t)(bn + swid * 8) * K_DIM; // SGPR
    int kst = 0;                                          // scalar k of staged tile

    // --- accumulators: per-wave 128x64 output, quadrants [m][n], frags [mi][ni]
    f32x4 acc[2][2][4][2];
#pragma unroll
    for (int m = 0; m < 2; ++m)
#pragma unroll
        for (int n = 0; n < 2; ++n)
#pragma unroll
            for (int mi = 0; mi < 4; ++mi)
#pragma unroll
                for (int ni = 0; ni < 2; ++ni) acc[m][n][mi][ni] = (f32x4)(0.0f);

    bf16x8 af[2][2][4];   // A frags [m-half][kk][mi]
    bf16x8 bf[2][2][2];   // B frags [n-half][kk][ni]

    const int fr = lane & 15;   // frag row
    const int fq = lane >> 4;   // quad
    const int fx = fr & 7;      // read-side swizzle xor

    const int e0 = (fq ^ fx) << 3;                      // kk=0 chunk, elements
    const int dK = (fx & 4) ? -32 : 32;                 // kk=1 chunk delta (elems)
    const __hip_bfloat16* aPtr[2];
    const __hip_bfloat16* bPtr[2];
    aPtr[0] = &lsA[0][0] + ((wr << 6) + fr) * 64 + e0;
    aPtr[1] = &lsA[1][0] + ((wr << 6) + fr) * 64 + e0;
    bPtr[0] = &lsB[0][0] + ((wc << 5) + fr) * 64 + e0;
    bPtr[1] = &lsB[1][0] + ((wc << 5) + fr) * 64 + e0;

// Stage A-half h of the tile at scalar k-offset kst into buffer p (2 gloads).
#define STAGE_A(h, p) do {                                                     \
    gload_lds16(Wb + aoffu + (h)*(128*K_DIM) + kst + loff,                     \
                &lsA[(p)*2 + (h)][swid << 9]);                                 \
    gload_lds16(Wb + aoffu + (h)*(128*K_DIM) + (64*K_DIM) + kst + loff,        \
                &lsA[(p)*2 + (h)][(swid + 8) << 9]);                           \
} while (0)

#define STAGE_B(h, p) do {                                                     \
    gload_lds16(Xb + boffu + (h)*(128*K_DIM) + kst + loff,                     \
                &lsB[(p)*2 + (h)][swid << 9]);                                 \
    gload_lds16(Xb + boffu + (h)*(128*K_DIM) + (64*K_DIM) + kst + loff,        \
                &lsB[(p)*2 + (h)][(swid + 8) << 9]);                           \
} while (0)

// 8 ds_read_b128: A-half h of buffer p -> af[h]
#define LOAD_AH(p, h) do {                                                     \
    const __hip_bfloat16* _pa = aPtr[h] + (p) * 16384;                         \
    af[h][0][0] = *(const bf16x8*)(const void*)(_pa);                          \
    af[h][0][1] = *(const bf16x8*)(const void*)(_pa + 1024);                   \
    af[h][0][2] = *(const bf16x8*)(const void*)(_pa + 2048);                   \
    af[h][0][3] = *(const bf16x8*)(const void*)(_pa + 3072);                   \
    af[h][1][0] = *(const bf16x8*)(const void*)(_pa + dK);                     \
    af[h][1][1] = *(const bf16x8*)(const void*)(_pa + dK + 1024);              \
    af[h][1][2] = *(const bf16x8*)(const void*)(_pa + dK + 2048);              \
    af[h][1][3] = *(const bf16x8*)(const void*)(_pa + dK + 3072);              \
} while (0)

// 4 ds_read_b128: B-half h of buffer p -> bf[h]
#define LOAD_BH(p, h) do {                                                     \
    const __hip_bfloat16* _pb = bPtr[h] + (p) * 16384;                         \
    bf[h][0][0] = *(const bf16x8*)(const void*)(_pb);                          \
    bf[h][0][1] = *(const bf16x8*)(const void*)(_pb + 1024);                   \
    bf[h][1][0] = *(const bf16x8*)(const void*)(_pb + dK);                     \
    bf[h][1][1] = *(const bf16x8*)(const void*)(_pb + dK + 1024);              \
} while (0)

#define MMA(m, n) do {                                                         \
    __builtin_amdgcn_s_setprio(1);                                             \
    _Pragma("unroll") for (int kk = 0; kk < 2; ++kk)                           \
    _Pragma("unroll") for (int mi = 0; mi < 4; ++mi)                           \
    _Pragma("unroll") for (int ni = 0; ni < 2; ++ni)                           \
        acc[m][n][mi][ni] = __builtin_amdgcn_mfma_f32_16x16x32_bf16(           \
            af[m][kk][mi], bf[n][kk][ni], acc[m][n][mi][ni], 0, 0, 0);         \
    __builtin_amdgcn_s_setprio(0);                                             \
} while (0)

// HARDENED barrier: s_barrier + compiler-level memory fence (0 instructions).
// s_barrier alone has no memory effects in LLVM's model -> ds_reads placed
// after it may hoist above it (the R9/R10 race). The empty asm pins them.
#define BAR()        do { __builtin_amdgcn_s_barrier();                        \
                          asm volatile("" ::: "memory"); } while (0)
#define WAIT_LGKM(N) asm volatile("s_waitcnt lgkmcnt(" #N ")" ::: "memory")
#define WAIT_VM(N)   asm volatile("s_waitcnt vmcnt(" #N ")" ::: "memory")

    // p = this tile's buffer, q = p^1. STG: stage tile t+2 into p.
    // VMW: vm wait at ph1-end. NRA/NRB: read-ahead of next tile's A0/B0.
    // LG2: lgkm count at ph2 (8 steady; 0 at tile 63 where NRA is empty).
#define TILE(p, STG, VMW, NRA, NRB, LG2) do {                                  \
    /* ph0 */                                                                  \
    WAIT_LGKM(0);                    /* prev read-ahead complete */            \
    LOAD_BH(p, 1);                   /* 4 ds_read -> bf[1] */                  \
    MMA(0, 0);                       /* af[0] x bf[0] */                       \
    BAR();                                                                     \
    /* ph1 */                                                                  \
    LOAD_AH(p, 1);                   /* 8 ds_read -> af[1] */                  \
    if (STG) STAGE_A(0, p);          /* 2 gloads (t+2 A0) */                   \
    WAIT_LGKM(8);                    /* B1 done (oldest 4 of 12) */            \
    MMA(0, 1);                       /* af[0] x bf[1] */                       \
    VMW;                             /* t+1 fully landed (outst 10 -> 2) */    \
    BAR();                                                                     \
    /* ph2 */                                                                  \
    NRA;                             /* 8 ds_read -> af[0] (next A0) */        \
    if (STG) { STAGE_B(0, p); STAGE_B(1, p); }   /* 4 gloads (t+2 B) */        \
    LG2;                             /* A1 done (oldest 8 of 16) */            \
    MMA(1, 0);                       /* af[1] x bf[0] (B0 not yet clobbered)*/ \
    BAR();                                                                     \
    /* ph3 */                                                                  \
    NRB;                             /* 4 ds_read -> bf[0] (next B0) */        \
    if (STG) STAGE_A(1, p);          /* 2 gloads (t+2 A1) */                   \
    MMA(1, 1);                       /* af[1] x bf[1] */                       \
    BAR();                                                                     \
    if (STG) kst += 64;                                                        \
} while (0)

#define NRA0 LOAD_AH(1, 0)   /* next = buf1 */
#define NRB0 LOAD_BH(1, 0)
#define NRA1 LOAD_AH(0, 0)   /* next = buf0 */
#define NRB1 LOAD_BH(0, 0)

    // Prologue: stage tiles 0 (kst=0) and 1 (kst=64); every wave drains
    // tile0 (VM(8): 16 outstanding -> completes oldest 8); hardened BAR;
    // THEN the initial read-ahead of tile0's A0,B0 (cannot hoist: asm fence).
    STAGE_A(0, 0); STAGE_B(0, 0); STAGE_A(1, 0); STAGE_B(1, 0);
    kst = 64;
    STAGE_A(0, 1); STAGE_B(0, 1); STAGE_A(1, 1); STAGE_B(1, 1);
    kst = 128;
    WAIT_VM(8);
    BAR();
    LOAD_AH(0, 0); LOAD_BH(0, 0);        // 12 reads: tile0 A0,B0

    // Main loop: tiles 0..61 (31 iterations x 2 tiles, steady vmcnt(2)).
    for (int it = 0; it < 31; ++it) {
        TILE(0, 1, WAIT_VM(2), NRA0, NRB0, WAIT_LGKM(8));
        TILE(1, 1, WAIT_VM(2), NRA1, NRB1, WAIT_LGKM(8));
    }
    // Tile 62: no staging; VM(0) at ph1-end drains tile 63's 8 stages before
    // the ph2/ph3 read-ahead of tile 63.
    TILE(0, 0, WAIT_VM(0), NRA0, NRB0, WAIT_LGKM(8));
    // Tile 63: pure compute; LG2=lgkm(0) completes A1 (no nA0 behind it).
    TILE(1, 0, (void)0, (void)0, (void)0, WAIT_LGKM(0));

#undef NRA0
#undef NRB0
#undef NRA1
#undef NRB1
#undef TILE
#undef WAIT_VM
#undef WAIT_LGKM
#undef BAR
#undef MMA
#undef LOAD_BH
#undef LOAD_AH
#undef STAGE_B
#undef STAGE_A

    // Epilogue: C/D layout col = lane&15, row = (lane>>4)*4 + reg.
#pragma unroll
    for (int n = 0; n < 2; ++n)
#pragma unroll
        for (int ni = 0; ni < 2; ++ni) {
            const int col = bn + n * 128 + (wc << 5) + (ni << 4) + fr;
            const float bv = bias[col];
#pragma unroll
            for (int m = 0; m < 2; ++m)
#pragma unroll
                for (int mi = 0; mi < 4; ++mi) {
                    const int r0 = bm + m * 128 + (wr << 6) + (mi << 4) + (fq << 2);
#pragma unroll
                    for (int i = 0; i < 4; ++i)
                        C[(size_t)(r0 + i) * K_DIM + col] = acc[m][n][mi][ni][i] + bv;
                }
        }
}

// ---------------------------------------------------------------------------
extern "C" void kernel_launch(void* const* d_in, const int* in_sizes, int n_in,
                              void* d_out, int out_size, void* d_ws, size_t ws_size,
                              hipStream_t stream)
{
    (void)in_sizes; (void)n_in; (void)out_size; (void)ws_size;

    const float* x    = (const float*)d_in[0];
    KronPtrs P;
    for (int i = 0; i < 8; ++i) {
        P.a[i] = (const float*)d_in[1 + i];
        P.b[i] = (const float*)d_in[9 + i];
    }
    const float* bias = (const float*)d_in[17];

    __hip_bfloat16* Wb = (__hip_bfloat16*)d_ws;                               // 32 MiB
    __hip_bfloat16* Xb = (__hip_bfloat16*)((char*)d_ws +
                          (size_t)K_DIM * K_DIM * sizeof(__hip_bfloat16));    // 32 MiB
    float* y = (float*)d_out;

    prologue_kernel<<<12288, 256, 0, stream>>>(P, x, Wb, Xb);

    gemm_kernel<<<256, 512, 0, stream>>>(Wb, Xb, bias, y);
}

// Round 10
// 267.780 us; speedup vs baseline: 1.0325x; 1.0325x over previous
//
#include <hip/hip_runtime.h>
#include <hip/hip_bf16.h>
#include <cstdint>
#include <cstddef>

#define K_DIM 4096

typedef __bf16 bf16x8 __attribute__((ext_vector_type(8)));
typedef float  f32x4  __attribute__((ext_vector_type(4)));
typedef unsigned short ushort8 __attribute__((ext_vector_type(8)));

struct KronPtrs { const float* a[8]; const float* b[8]; };

// ---------------------------------------------------------------------------
// Fused prologue (unchanged).
// ---------------------------------------------------------------------------
__global__ __launch_bounds__(256) void prologue_kernel(
        KronPtrs P,
        const float* __restrict__ x,
        __hip_bfloat16* __restrict__ Wb,
        __hip_bfloat16* __restrict__ Xb)
{
    __shared__ __align__(16) float sa[1080];
    __shared__ __align__(16) float sb[1080];

    const int tid = threadIdx.x;

    if (blockIdx.x < 8192) {
        const size_t t = (size_t)blockIdx.x * 256 + tid;
        const size_t o = t * 8;
        const float4 v0 = *(const float4*)(x + o);
        const float4 v1 = *(const float4*)(x + o + 4);
        union { __hip_bfloat16 h[8]; ushort8 v; } u;
        u.h[0] = __float2bfloat16(v0.x);
        u.h[1] = __float2bfloat16(v0.y);
        u.h[2] = __float2bfloat16(v0.z);
        u.h[3] = __float2bfloat16(v0.w);
        u.h[4] = __float2bfloat16(v1.x);
        u.h[5] = __float2bfloat16(v1.y);
        u.h[6] = __float2bfloat16(v1.z);
        u.h[7] = __float2bfloat16(v1.w);
        *(ushort8*)(void*)(Xb + o) = u.v;
        return;
    }

    const int row = blockIdx.x - 8192;

#define STAGE(IDX, MA, LB, OA, OB)                                             \
    {                                                                          \
        const int mb_ = 1 << (LB);                                             \
        const float* ap = P.a[IDX] + (size_t)(row >> (LB)) * (MA);             \
        const float* bp = P.b[IDX] + (size_t)(row & (mb_ - 1)) * mb_;          \
        for (int i = tid; i < (MA); i += 256) sa[(OA) + i] = ap[i];            \
        for (int i = tid; i < mb_;  i += 256) sb[(OB) + i] = bp[i];            \
    }

    STAGE(0,  64, 6,   0,    0)
    STAGE(1,  64, 6,  64,   64)
    STAGE(2,  32, 7, 128,  128)
    STAGE(3, 128, 5, 160,  256)
    STAGE(4,  16, 8, 288,  288)
    STAGE(5, 256, 4, 304,  544)
    STAGE(6,   8, 9, 560,  560)
    STAGE(7, 512, 3, 568, 1072)
#undef STAGE

    __syncthreads();

    const float s = 0.17677669529663687f;  // 1 / (2*sqrt(8))
    const int q0 = tid << 4;

#pragma unroll
    for (int g = 0; g < 2; ++g) {
        const int q8 = q0 + (g << 3);
        float acc[8] = {0.f,0.f,0.f,0.f,0.f,0.f,0.f,0.f};

#define KTERM(LB, OA, OB)                                                      \
    {                                                                          \
        const int mb_   = 1 << (LB);                                           \
        const float av  = sa[(OA) + (q8 >> (LB))];                             \
        const float* bp = sb + (OB) + (q8 & (mb_ - 1));                        \
        const float4 x0 = *(const float4*)(bp);                                \
        const float4 x1 = *(const float4*)(bp + 4);                            \
        acc[0] += av * x0.x; acc[1] += av * x0.y;                              \
        acc[2] += av * x0.z; acc[3] += av * x0.w;                              \
        acc[4] += av * x1.x; acc[5] += av * x1.y;                              \
        acc[6] += av * x1.z; acc[7] += av * x1.w;                              \
    }

        KTERM(6,   0,    0)
        KTERM(6,  64,   64)
        KTERM(7, 128,  128)
        KTERM(5, 160,  256)
        KTERM(8, 288,  288)
        KTERM(4, 304,  544)
        KTERM(9, 560,  560)
        KTERM(3, 568, 1072)
#undef KTERM

        union { __hip_bfloat16 h[8]; ushort8 v; } u;
#pragma unroll
        for (int i = 0; i < 8; ++i) u.h[i] = __float2bfloat16(acc[i] * s);
        *(ushort8*)(void*)(Wb + (size_t)row * K_DIM + q8) = u.v;
    }
}

// ---------------------------------------------------------------------------
// GEMM R13 = R12's 2-phase pipeline + THE TILE-0 WAR FIX.
//
// Root cause of R9/R10/R12 failures (and R8/R11 immunity): in steady state,
// P1's stage of tile t+2 into buf p's A0/B0 is WAR-safe because the PREVIOUS
// P2 ends with lgkm(0)+BAR — every wave's read-ahead of that region drains
// before the stage can issue. The PRE-LOOP read-ahead had no such tail: tile
// 0's P1 issued its DMA stage (tile 2 -> buf0 A0/B0) while other waves'
// pre-loop ds_reads of buf0 A0/B0 were still in flight (first counted lgkm
// came after the stage issue). DMA L2-hit (~200cy, Wb/Xb L2-resident after
// the prologue kernel) vs contended ds_read (~120cy+) -> timing race ->
// corrupt tile-0 fragments. The 4-phase variants drained the pre-loop reads
// in ph0 (lgkm(4)) BEFORE ph1's first stage — that's why R8/R11 were green.
// FIX: pre-loop tail = lgkm(0); BAR — identical to the steady-state P2 tail.
//
// Steady state per tile t (buffer p, q=p^1), 2 barriers, 2x32-MFMA:
//  P1: read B1(p)[4] + A1(p)[8]; stage A0B0(t+2 -> p);
//      lgkm(8); MMA(0,0); MMA(0,1); lgkm(0); vmcnt(4) [t+1 landed]; BAR
//  P2: read A0(q)[8]; stage A1B1(t+2 -> p); MMA(1,0); read B0(q)[4];
//      MMA(1,1); lgkm(0); BAR
// vm ledger: at P1-end outstanding = [t+1 A0B0, t+1 A1B1, t+2 A0B0(newest)]
// -> vmcnt(4) completes all of t+1; fenced BAR publishes to all waves before
// P2 reads buf q. WAR: every stage targets a region whose readers drained at
// an exact lgkm(0) >=1 fenced barrier earlier. Stages/reads are pinned inside
// their phase by the asm "memory" fences (BAR = s_barrier + empty asm fence;
// s_barrier alone is IntrNoMem). Intra-wave reg deps: compiler-enforced.
// Tail: tile62 vmcnt(0) drains tile63 before its read-ahead; tile63 bare.
// ---------------------------------------------------------------------------
__device__ __forceinline__ void gload_lds16(const void* g, void* l)
{
    __builtin_amdgcn_global_load_lds((const __attribute__((address_space(1))) void*)g,
                                     (__attribute__((address_space(3))) void*)l,
                                     16, 0, 0);
}

__global__ __launch_bounds__(512) void gemm_kernel(
        const __hip_bfloat16* __restrict__ Wb,
        const __hip_bfloat16* __restrict__ Xb,
        const float* __restrict__ bias,
        float* __restrict__ C)
{
    // [buf*2 + half][128 rows * 64 cols]
    __shared__ __align__(16) __hip_bfloat16 lsA[4][8192];   // 64 KiB
    __shared__ __align__(16) __hip_bfloat16 lsB[4][8192];   // 64 KiB

    const int tid  = threadIdx.x;
    const int lane = tid & 63;
    const int wid  = tid >> 6;    // 0..7
    const int swid = __builtin_amdgcn_readfirstlane(wid);   // wave-uniform SGPR
    const int wr   = wid >> 2;    // 0..1 (M)
    const int wc   = wid & 3;     // 0..3 (N)

    // XCD-aware bijective swizzle of the 256-block grid (16x16 tiles).
    const int bid = blockIdx.x;
    const int lin = (bid & 7) * 32 + (bid >> 3);
    const int bm  = (lin >> 4) << 8;
    const int bn  = (lin & 15) << 8;

    // --- staging addressing: scalar bases + ONE per-lane offset ---
    const int sr = lane >> 3;            // row within 8-row chunk
    const int lc = (lane & 7) ^ sr;      // logical 16B chunk to fetch (swizzle)
    const int loff = sr * K_DIM + lc * 8;                 // per-lane, 1 VGPR
    const size_t aoffu = (size_t)(bm + swid * 8) * K_DIM; // SGPR
    const size_t boffu = (size_t)(bn + swid * 8) * K_DIM; // SGPR
    int kst = 0;                                          // scalar k of staged tile

    // --- accumulators: per-wave 128x64 output, quadrants [m][n], frags [mi][ni]
    f32x4 acc[2][2][4][2];
#pragma unroll
    for (int m = 0; m < 2; ++m)
#pragma unroll
        for (int n = 0; n < 2; ++n)
#pragma unroll
            for (int mi = 0; mi < 4; ++mi)
#pragma unroll
                for (int ni = 0; ni < 2; ++ni) acc[m][n][mi][ni] = (f32x4)(0.0f);

    bf16x8 af[2][2][4];   // A frags [m-half][kk][mi]
    bf16x8 bf[2][2][2];   // B frags [n-half][kk][ni]

    const int fr = lane & 15;   // frag row
    const int fq = lane >> 4;   // quad
    const int fx = fr & 7;      // read-side swizzle xor

    const int e0 = (fq ^ fx) << 3;                      // kk=0 chunk, elements
    const int dK = (fx & 4) ? -32 : 32;                 // kk=1 chunk delta (elems)
    const __hip_bfloat16* aPtr[2];
    const __hip_bfloat16* bPtr[2];
    aPtr[0] = &lsA[0][0] + ((wr << 6) + fr) * 64 + e0;
    aPtr[1] = &lsA[1][0] + ((wr << 6) + fr) * 64 + e0;
    bPtr[0] = &lsB[0][0] + ((wc << 5) + fr) * 64 + e0;
    bPtr[1] = &lsB[1][0] + ((wc << 5) + fr) * 64 + e0;

// Stage A-half h of the tile at scalar k-offset kst into buffer p (2 gloads).
#define STAGE_A(h, p) do {                                                     \
    gload_lds16(Wb + aoffu + (h)*(128*K_DIM) + kst + loff,                     \
                &lsA[(p)*2 + (h)][swid << 9]);                                 \
    gload_lds16(Wb + aoffu + (h)*(128*K_DIM) + (64*K_DIM) + kst + loff,        \
                &lsA[(p)*2 + (h)][(swid + 8) << 9]);                           \
} while (0)

#define STAGE_B(h, p) do {                                                     \
    gload_lds16(Xb + boffu + (h)*(128*K_DIM) + kst + loff,                     \
                &lsB[(p)*2 + (h)][swid << 9]);                                 \
    gload_lds16(Xb + boffu + (h)*(128*K_DIM) + (64*K_DIM) + kst + loff,        \
                &lsB[(p)*2 + (h)][(swid + 8) << 9]);                           \
} while (0)

// 8 ds_read_b128: A-half h of buffer p -> af[h]
#define LOAD_AH(p, h) do {                                                     \
    const __hip_bfloat16* _pa = aPtr[h] + (p) * 16384;                         \
    af[h][0][0] = *(const bf16x8*)(const void*)(_pa);                          \
    af[h][0][1] = *(const bf16x8*)(const void*)(_pa + 1024);                   \
    af[h][0][2] = *(const bf16x8*)(const void*)(_pa + 2048);                   \
    af[h][0][3] = *(const bf16x8*)(const void*)(_pa + 3072);                   \
    af[h][1][0] = *(const bf16x8*)(const void*)(_pa + dK);                     \
    af[h][1][1] = *(const bf16x8*)(const void*)(_pa + dK + 1024);              \
    af[h][1][2] = *(const bf16x8*)(const void*)(_pa + dK + 2048);              \
    af[h][1][3] = *(const bf16x8*)(const void*)(_pa + dK + 3072);              \
} while (0)

// 4 ds_read_b128: B-half h of buffer p -> bf[h]
#define LOAD_BH(p, h) do {                                                     \
    const __hip_bfloat16* _pb = bPtr[h] + (p) * 16384;                         \
    bf[h][0][0] = *(const bf16x8*)(const void*)(_pb);                          \
    bf[h][0][1] = *(const bf16x8*)(const void*)(_pb + 1024);                   \
    bf[h][1][0] = *(const bf16x8*)(const void*)(_pb + dK);                     \
    bf[h][1][1] = *(const bf16x8*)(const void*)(_pb + dK + 1024);              \
} while (0)

#define MMA(m, n) do {                                                         \
    __builtin_amdgcn_s_setprio(1);                                             \
    _Pragma("unroll") for (int kk = 0; kk < 2; ++kk)                           \
    _Pragma("unroll") for (int mi = 0; mi < 4; ++mi)                           \
    _Pragma("unroll") for (int ni = 0; ni < 2; ++ni)                           \
        acc[m][n][mi][ni] = __builtin_amdgcn_mfma_f32_16x16x32_bf16(           \
            af[m][kk][mi], bf[n][kk][ni], acc[m][n][mi][ni], 0, 0, 0);         \
    __builtin_amdgcn_s_setprio(0);                                             \
} while (0)

// HARDENED barrier: s_barrier + compiler-level memory fence (0 instructions).
#define BAR()        do { __builtin_amdgcn_s_barrier();                        \
                          asm volatile("" ::: "memory"); } while (0)
#define WAIT_LGKM(N) asm volatile("s_waitcnt lgkmcnt(" #N ")" ::: "memory")
#define WAIT_VM(N)   asm volatile("s_waitcnt vmcnt(" #N ")" ::: "memory")

    // p = this tile's buffer, q = p^1 (next tile's buffer).
    // STG: stage tile t+2 into p.  VM: vm drain at P1-end (before barrier).
    // NRA/NRB: read-ahead of next tile's A0 / B0 (into af[0]/bf[0]).
#define TILE(p, STG, VM, NRA, NRB) do {                                        \
    /* ---- P1 ---- */                                                         \
    LOAD_BH(p, 1);                       /* 4 ds_read  -> bf[1] */             \
    LOAD_AH(p, 1);                       /* 8 ds_read  -> af[1] */             \
    if (STG) { STAGE_A(0, p); STAGE_B(0, p); }   /* 4 gloads (t+2) */          \
    WAIT_LGKM(8);                        /* B1 done */                         \
    MMA(0, 0); MMA(0, 1);                /* 32 MFMA; A1 drains under */        \
    WAIT_LGKM(0);                        /* A1 done (cheap) */                 \
    VM;                                  /* t+1 landed (before barrier) */     \
    BAR();                                                                     \
    /* ---- P2 ---- */                                                         \
    NRA;                                 /* 8 ds_read -> af[0] (next A0) */    \
    if (STG) { STAGE_A(1, p); STAGE_B(1, p); }   /* 4 gloads (t+2) */          \
    MMA(1, 0);                           /* consumes bf[0] before clobber */   \
    NRB;                                 /* 4 ds_read -> bf[0] (next B0) */    \
    MMA(1, 1);                                                                 \
    WAIT_LGKM(0);                        /* read-ahead drained (WAR tail) */   \
    BAR();                                                                     \
    if (STG) kst += 64;                                                        \
} while (0)

#define NRA0 LOAD_AH(1, 0)   /* next = buf1 */
#define NRB0 LOAD_BH(1, 0)
#define NRA1 LOAD_AH(0, 0)   /* next = buf0 */
#define NRB1 LOAD_BH(0, 0)

    // Prologue: stage tiles 0 (kst=0) and 1 (kst=64); drain tile0 on every
    // wave (vmcnt(8): 16 outstanding -> oldest 8 = tile0 complete); fenced
    // barrier; initial read-ahead of tile0's A0,B0; THEN THE TILE-0 WAR FIX:
    // lgkm(0)+BAR — the exact steady-state P2 tail — so tile0 P1's stage of
    // tile2 into buf0 A0/B0 cannot land over any wave's in-flight read.
    STAGE_A(0, 0); STAGE_B(0, 0); STAGE_A(1, 0); STAGE_B(1, 0);
    kst = 64;
    STAGE_A(0, 1); STAGE_B(0, 1); STAGE_A(1, 1); STAGE_B(1, 1);
    kst = 128;
    WAIT_VM(8);
    BAR();
    LOAD_AH(0, 0); LOAD_BH(0, 0);        // 12 reads: tile0 A0,B0
    WAIT_LGKM(0);                        // drain them (all waves)
    BAR();                               // publish before tile0 P1's stage

    // Main loop: tiles 0..61 (31 iterations x 2 tiles, steady vmcnt(4)).
    for (int it = 0; it < 31; ++it) {
        TILE(0, 1, WAIT_VM(4), NRA0, NRB0);
        TILE(1, 1, WAIT_VM(4), NRA1, NRB1);
    }
    // Tile 62: no staging; vmcnt(0) drains tile 63's stages before its
    // read-ahead.
    TILE(0, 0, WAIT_VM(0), NRA0, NRB0);
    // Tile 63: pure compute, no staging, no read-ahead.
    TILE(1, 0, (void)0, (void)0, (void)0);

#undef NRA0
#undef NRB0
#undef NRA1
#undef NRB1
#undef TILE
#undef WAIT_VM
#undef WAIT_LGKM
#undef BAR
#undef MMA
#undef LOAD_BH
#undef LOAD_AH
#undef STAGE_B
#undef STAGE_A

    // Epilogue: C/D layout col = lane&15, row = (lane>>4)*4 + reg.
#pragma unroll
    for (int n = 0; n < 2; ++n)
#pragma unroll
        for (int ni = 0; ni < 2; ++ni) {
            const int col = bn + n * 128 + (wc << 5) + (ni << 4) + fr;
            const float bv = bias[col];
#pragma unroll
            for (int m = 0; m < 2; ++m)
#pragma unroll
                for (int mi = 0; mi < 4; ++mi) {
                    const int r0 = bm + m * 128 + (wr << 6) + (mi << 4) + (fq << 2);
#pragma unroll
                    for (int i = 0; i < 4; ++i)
                        C[(size_t)(r0 + i) * K_DIM + col] = acc[m][n][mi][ni][i] + bv;
                }
        }
}

// ---------------------------------------------------------------------------
extern "C" void kernel_launch(void* const* d_in, const int* in_sizes, int n_in,
                              void* d_out, int out_size, void* d_ws, size_t ws_size,
                              hipStream_t stream)
{
    (void)in_sizes; (void)n_in; (void)out_size; (void)ws_size;

    const float* x    = (const float*)d_in[0];
    KronPtrs P;
    for (int i = 0; i < 8; ++i) {
        P.a[i] = (const float*)d_in[1 + i];
        P.b[i] = (const float*)d_in[9 + i];
    }
    const float* bias = (const float*)d_in[17];

    __hip_bfloat16* Wb = (__hip_bfloat16*)d_ws;                               // 32 MiB
    __hip_bfloat16* Xb = (__hip_bfloat16*)((char*)d_ws +
                          (size_t)K_DIM * K_DIM * sizeof(__hip_bfloat16));    // 32 MiB
    float* y = (float*)d_out;

    prologue_kernel<<<12288, 256, 0, stream>>>(P, x, Wb, Xb);

    gemm_kernel<<<256, 512, 0, stream>>>(Wb, Xb, bias, y);
}